// Round 15
// baseline (124.561 us; speedup 1.0000x reference)
//
#include <hip/hip_runtime.h>
#include <hip/hip_bf16.h>

#define BATCH  4
#define SEQ    4096
#define DMODEL 1024
#define HDIM   128
#define MROWS  (BATCH * SEQ)   // 16384
#define NT32   (SEQ / 32)      // 128 q-tiles (32 rows) per batch
#define T32    (BATCH * NT32)  // 512
#define NS     8               // KV splits per q-tile (bf16 partials)

// qkv GEMM tile: BM=128 -> 24 MFMA/wave/K-tile (4x barrier amortization vs
// BM=32's 6); grid 512 = 2 blocks/CU, LDS 56KB.
#define BM 128
#define BN 96
#define BK 64
#define KT (DMODEL / BK)       // 16

typedef __attribute__((ext_vector_type(8)))  short short8;
typedef __attribute__((ext_vector_type(4)))  float floatx4;
typedef __attribute__((ext_vector_type(16))) float floatx16;
typedef unsigned int u32;

static __device__ __forceinline__ short f2bf(float f) {
    __hip_bfloat16 h = __float2bfloat16(f);
    union { __hip_bfloat16 h; short s; } u; u.h = h;
    return u.s;
}

static __device__ __forceinline__ float bf2f(unsigned short s) {
    union { u32 u; float f; } v; v.u = ((u32)s) << 16;
    return v.f;
}

static __device__ __forceinline__ short8 ld8(const unsigned short* p) {
    return *reinterpret_cast<const short8*>(p);
}

// async global->LDS, 16 B per lane; LDS dest = wave-uniform base + lane*16.
static __device__ __forceinline__ void gload_lds16(const void* g, void* l) {
    __builtin_amdgcn_global_load_lds(
        (const __attribute__((address_space(1))) unsigned int*)g,
        (__attribute__((address_space(3))) unsigned int*)l,
        16, 0, 0);
}

// pack two f32 -> one u32 of two bf16 (lo = a, hi = b)
static __device__ __forceinline__ u32 cvtpk_bf16(float a, float b) {
    u32 r;
    asm("v_cvt_pk_bf16_f32 %0, %1, %2" : "=v"(r) : "v"(a), "v"(b));
    return r;
}

// a' = {lanes<32: a ; lanes>=32: b from partner(lane-32)}
// b' = {lanes<32: a from partner(lane+32) ; lanes>=32: b}
static __device__ __forceinline__ void swap_halves(u32& a, u32& b) {
#if __has_builtin(__builtin_amdgcn_permlane32_swap)
    typedef __attribute__((ext_vector_type(2))) int int2v;
    int2v r = __builtin_amdgcn_permlane32_swap((int)a, (int)b, false, false);
    a = (u32)r[0]; b = (u32)r[1];
#else
    u32 ap = (u32)__shfl_xor((int)a, 32);
    u32 bp = (u32)__shfl_xor((int)b, 32);
    const bool hih = (threadIdx.x & 32) != 0;
    u32 na = hih ? bp : a;
    u32 nb = hih ? b : ap;
    a = na; b = nb;
#endif
}

// ===========================================================================
// FRAGMENT-TILED LAYOUTS (round-12 proven — attn loads are 1KB coalesced):
//  qt/kt: (b,s,d) at ((b*NT32+s/32)*8 + d/16)*512 + ((d/8)%2*32 + s%32)*8 + d%8
//  vtl:   (b,s,d) at ((b*NT32+s/32)*8 + (d/32)*2 + (s%32)/16)*512
//                     + ((s/8)%2*32 + d%32)*8 + s%8
// ===========================================================================

// ---------------------------------------------------------------------------
// W = [Wq;Wk;Wv] fp32 -> bf16, Wq pre-scaled by 1/sqrt(H). One launch.
// ---------------------------------------------------------------------------
__global__ __launch_bounds__(256) void cvt_w_kernel(
    const float* __restrict__ Wq, const float* __restrict__ Wk,
    const float* __restrict__ Wv, unsigned short* __restrict__ wbf)
{
    const int n8w = HDIM * DMODEL / 8;                // 16384
    int i = blockIdx.x * 256 + threadIdx.x;
    if (i >= 3 * n8w) return;
    const int which = i / n8w;
    const int j = i - which * n8w;
    const float* src = (which == 0) ? Wq : (which == 1) ? Wk : Wv;
    const float scale = (which == 0) ? 0.08838834764831845f : 1.0f;
    const float4* s4 = reinterpret_cast<const float4*>(src);
    float4 a = s4[2 * j];
    float4 b = s4[2 * j + 1];
    short8 o;
    o[0] = f2bf(a.x * scale); o[1] = f2bf(a.y * scale);
    o[2] = f2bf(a.z * scale); o[3] = f2bf(a.w * scale);
    o[4] = f2bf(b.x * scale); o[5] = f2bf(b.y * scale);
    o[6] = f2bf(b.z * scale); o[7] = f2bf(b.w * scale);
    reinterpret_cast<short8*>(wbf)[i] = o;
}

// ---------------------------------------------------------------------------
// QKV projection, double-buffered LDS GEMM (round-12 proven staging algebra,
// BM scaled 64->128 for barrier amortization: 24 MFMA/wave/K-tile).
// A: fp32 reg-staged one tile ahead (ar=tid>>1, half akh=tid&1, 32 floats),
//    cvt, XOR-swizzled ds_write at unit (akh*4+j)^(ar&7).
// B: async gload_lds w/ pre-swizzled per-lane source unit (rule #21).
// Read XOR = (kk*4+lh)^(lr&7); valid: all fragment rows = lr mod 8
// (offsets 64/48/16 are 0 mod 8).
// 4 waves 2x2: each wave 64x48 = 4x3 frags, 24 MFMA per K-tile.
// ---------------------------------------------------------------------------
__global__ __launch_bounds__(256) void qkv_kernel(
    const float* __restrict__ x,             // [MROWS][DMODEL] fp32
    const unsigned short* __restrict__ wbf,  // [384][DMODEL] bf16
    unsigned short* __restrict__ qt,         // tiled Q
    unsigned short* __restrict__ kt,         // tiled K
    unsigned short* __restrict__ vtl)        // tiled V
{
    __shared__ __align__(16) unsigned short A_lds[2][BM][BK];  // 32 KB
    __shared__ __align__(16) unsigned short B_lds[2][BN][BK];  // 24 KB

    // XCD chunking: 512 = 8 * 64; the 4 N-blocks of an m-panel share an XCD
    const int raw  = blockIdx.x;
    const int vid  = (raw & 7) * 64 + (raw >> 3);
    const int mblk = vid >> 2;
    const int nblk = vid & 3;
    const int m0   = mblk * BM;
    const int n0   = nblk * BN;

    const int tid  = threadIdx.x;
    const int wv   = tid >> 6;
    const int lane = tid & 63;
    const int lr   = lane & 15;
    const int lh   = lane >> 4;
    const int wm   = wv >> 1;   // 0/1 -> M offset 0/64
    const int wn   = wv & 1;    // 0/1 -> N offset 0/48

    // A staging: thread -> row ar=tid>>1 (0..127), k-half akh=tid&1 (32 floats)
    const int ar  = tid >> 1;
    const int akh = tid & 1;
    const float* asrc = x + (size_t)(m0 + ar) * DMODEL + akh * 32;

    // B staging: lane -> row rbase+(lane>>3); source unit pre-swizzled
    const int brow  = lane >> 3;
    const int bunit = (lane & 7) ^ brow;

    floatx4 acc[4][3];
#pragma unroll
    for (int mf = 0; mf < 4; ++mf)
#pragma unroll
        for (int nf = 0; nf < 3; ++nf) acc[mf][nf] = (floatx4){0.f, 0.f, 0.f, 0.f};

    // ---- prologue: stage tile 0 into buffer 0 ----
    {
#pragma unroll
        for (int j = 0; j < 3; ++j) {
            const int rbase = (j * 4 + wv) * 8;
            gload_lds16(wbf + (size_t)(n0 + rbase + brow) * DMODEL + bunit * 8,
                        &B_lds[0][rbase][0]);
        }
#pragma unroll
        for (int j = 0; j < 4; ++j) {
            float4 f0 = *reinterpret_cast<const float4*>(asrc + j * 8);
            float4 f1 = *reinterpret_cast<const float4*>(asrc + j * 8 + 4);
            short8 v;
            v[0] = f2bf(f0.x); v[1] = f2bf(f0.y); v[2] = f2bf(f0.z); v[3] = f2bf(f0.w);
            v[4] = f2bf(f1.x); v[5] = f2bf(f1.y); v[6] = f2bf(f1.z); v[7] = f2bf(f1.w);
            const int u = (akh * 4 + j) ^ (ar & 7);
            *reinterpret_cast<short8*>(&A_lds[0][ar][u * 8]) = v;
        }
    }
    __syncthreads();

    for (int ktile = 0; ktile < KT; ++ktile) {
        const int cur = ktile & 1;
        const int nxt = cur ^ 1;
        float4 pf[8];
        if (ktile + 1 < KT) {
            // async B prefetch into other buffer; A -> regs
#pragma unroll
            for (int j = 0; j < 3; ++j) {
                const int rbase = (j * 4 + wv) * 8;
                gload_lds16(wbf + (size_t)(n0 + rbase + brow) * DMODEL
                                + (ktile + 1) * BK + bunit * 8,
                            &B_lds[nxt][rbase][0]);
            }
            const float* a = asrc + (ktile + 1) * BK;
#pragma unroll
            for (int j = 0; j < 4; ++j) {
                pf[2 * j]     = *reinterpret_cast<const float4*>(a + j * 8);
                pf[2 * j + 1] = *reinterpret_cast<const float4*>(a + j * 8 + 4);
            }
        }
        // ---- compute on cur: 2 k-steps of 32, 12 MFMA each ----
#pragma unroll
        for (int kk = 0; kk < 2; ++kk) {
            const int uswz = (kk * 4 + lh) ^ (lr & 7);
            short8 af[4], bfr[3];
#pragma unroll
            for (int mf = 0; mf < 4; ++mf)
                af[mf] = ld8(&A_lds[cur][wm * 64 + mf * 16 + lr][uswz * 8]);
#pragma unroll
            for (int nf = 0; nf < 3; ++nf)
                bfr[nf] = ld8(&B_lds[cur][wn * 48 + nf * 16 + lr][uswz * 8]);
#pragma unroll
            for (int mf = 0; mf < 4; ++mf)
#pragma unroll
                for (int nf = 0; nf < 3; ++nf)
                    acc[mf][nf] = __builtin_amdgcn_mfma_f32_16x16x32_bf16(
                        af[mf], bfr[nf], acc[mf][nf], 0, 0, 0);
        }
        if (ktile + 1 < KT) {
            // cvt + swizzled ds_write of A(nxt)
#pragma unroll
            for (int j = 0; j < 4; ++j) {
                short8 v;
                v[0] = f2bf(pf[2*j].x);   v[1] = f2bf(pf[2*j].y);
                v[2] = f2bf(pf[2*j].z);   v[3] = f2bf(pf[2*j].w);
                v[4] = f2bf(pf[2*j+1].x); v[5] = f2bf(pf[2*j+1].y);
                v[6] = f2bf(pf[2*j+1].z); v[7] = f2bf(pf[2*j+1].w);
                const int u = (akh * 4 + j) ^ (ar & 7);
                *reinterpret_cast<short8*>(&A_lds[nxt][ar][u * 8]) = v;
            }
        }
        __syncthreads();
    }

    // ---- epilogue: route to tiled q / k / v layouts (round-12 proven map) ----
#pragma unroll
    for (int nf = 0; nf < 3; ++nf) {
        const int c = n0 + wn * 48 + nf * 16 + lr;
#pragma unroll
        for (int mf = 0; mf < 4; ++mf) {
#pragma unroll
            for (int r = 0; r < 4; ++r) {
                const int gm = m0 + wm * 64 + mf * 16 + lh * 4 + r;
                const unsigned short vv = (unsigned short)f2bf(acc[mf][nf][r]);
                const int bb = gm >> 12;           // batch
                const int sv = gm & (SEQ - 1);     // seq pos
                const int t  = sv >> 5;            // 32-tile
                if (c < HDIM) {
                    const int d = c;
                    const size_t addr =
                        ((size_t)((bb * NT32 + t) * 8 + (d >> 4)) << 9)
                        + ((((d >> 3) & 1) * 32 + (sv & 31)) * 8) + (d & 7);
                    qt[addr] = vv;
                } else if (c < 2 * HDIM) {
                    const int d = c - HDIM;
                    const size_t addr =
                        ((size_t)((bb * NT32 + t) * 8 + (d >> 4)) << 9)
                        + ((((d >> 3) & 1) * 32 + (sv & 31)) * 8) + (d & 7);
                    kt[addr] = vv;
                } else {
                    const int d = c - 2 * HDIM;
                    const size_t addr =
                        ((size_t)((bb * NT32 + t) * 8 + (d >> 5) * 2 + ((sv >> 4) & 1)) << 9)
                        + ((((sv >> 3) & 1) * 32 + (d & 31)) * 8) + (sv & 7);
                    vtl[addr] = vv;
                }
            }
        }
    }
}

// ---------------------------------------------------------------------------
// Causal flash attention — round-12 proven (fragment-tiled coalesced loads).
// ---------------------------------------------------------------------------
__global__ __launch_bounds__(64) void attn_kernel(
    const unsigned short* __restrict__ qt,
    const unsigned short* __restrict__ kt,
    const unsigned short* __restrict__ vtl,
    unsigned short* __restrict__ pacc,   // [NS][T32][128][32] bf16
    float* __restrict__ pm,
    float* __restrict__ pl)
{
    const int bid  = blockIdx.x;
    const int xcd  = bid & 7;
    const int b    = xcd >> 1;                // batch <-> XCD pair
    const int par  = xcd & 1;
    const int idx  = bid >> 3;                // 0..511 within XCD
    const int s    = idx & 7;                 // split
    const int trk  = idx >> 3;                // 0..63 tile-rank on this XCD
    const int t32b = (NT32 - 1) - (trk * 2 + par);   // longest first
    const int q0   = t32b * 32;
    const int t32  = b * NT32 + t32b;
    const int lane = threadIdx.x & 63;
    const int l31  = lane & 31;
    const int hih  = lane >> 5;

    const int nkv   = q0 + 32;
    const int chunk = ((nkv + NS * 32 - 1) / (NS * 32)) * 32;
    const int lo    = s * chunk;
    const int hikv  = (lo + chunk < nkv) ? lo + chunk : nkv;
    const size_t mlbase = (size_t)(s * T32 + t32) * 32;

    if (lo >= hikv) {
        if (lane < 32) { pm[mlbase + l31] = -3.0e38f; pl[mlbase + l31] = 0.f; }
        return;
    }

    // Q fragments (coalesced tiled loads)
    const unsigned short* qtb =
        qt + ((size_t)((b * NT32 + t32b) * 8) << 9) + lane * 8;
    short8 qa[8];
#pragma unroll
    for (int ks = 0; ks < 8; ++ks) qa[ks] = ld8(qtb + (ks << 9));

    floatx16 acco[4];
#pragma unroll
    for (int db = 0; db < 4; ++db)
#pragma unroll
        for (int i = 0; i < 16; ++i) acco[db][i] = 0.f;
    float m_r = -3.0e38f, l_r = 0.f;

    for (int kv0 = lo; kv0 < hikv; kv0 += 32) {
        const int t = kv0 >> 5;
        const unsigned short* ktb =
            kt + ((size_t)((b * NT32 + t) * 8) << 9) + lane * 8;
        const unsigned short* vtb =
            vtl + ((size_t)((b * NT32 + t) * 8) << 9) + lane * 8;

        // ---- scores S^T[kv][q] = mfma(K, Q) ----
        floatx16 sc;
#pragma unroll
        for (int i = 0; i < 16; ++i) sc[i] = 0.f;
#pragma unroll
        for (int ks = 0; ks < 8; ++ks) {
            short8 kf = ld8(ktb + (ks << 9));
            sc = __builtin_amdgcn_mfma_f32_32x32x16_bf16(kf, qa[ks], sc, 0, 0, 0);
        }
        // ---- causal mask: only the diagonal tile ----
        if (kv0 == q0) {
#pragma unroll
            for (int r = 0; r < 16; ++r) {
                const int kvloc = (r & 3) + 8 * (r >> 2) + 4 * hih;
                if (kvloc > l31) sc[r] = -3.0e38f;
            }
        }
        // ---- lane-local max (tree) + cross-half ----
        float t8[8];
#pragma unroll
        for (int i = 0; i < 8; ++i) t8[i] = fmaxf(sc[i], sc[i + 8]);
        float t4a = fmaxf(t8[0], t8[4]), t4b = fmaxf(t8[1], t8[5]);
        float t4c = fmaxf(t8[2], t8[6]), t4d = fmaxf(t8[3], t8[7]);
        float pmax = fmaxf(fmaxf(t4a, t4b), fmaxf(t4c, t4d));
        pmax = fmaxf(pmax, __shfl_xor(pmax, 32));
        // ---- deferred rescale (T13, THR=8) ----
        if (__any(pmax > m_r + 8.f)) {
            const float mn  = fmaxf(m_r, pmax);
            const float fac = __expf(m_r - mn);
            m_r = mn; l_r *= fac;
#pragma unroll
            for (int db = 0; db < 4; ++db)
#pragma unroll
                for (int i = 0; i < 16; ++i) acco[db][i] *= fac;
        }
        // ---- p = exp(s - m), lane-local sum ----
        float p[16];
#pragma unroll
        for (int r = 0; r < 16; ++r) p[r] = __expf(sc[r] - m_r);
        float s8[8];
#pragma unroll
        for (int i = 0; i < 8; ++i) s8[i] = p[i] + p[i + 8];
        float s4a = s8[0] + s8[4], s4b = s8[1] + s8[5];
        float s4c = s8[2] + s8[6], s4d = s8[3] + s8[7];
        float ps = (s4a + s4b) + (s4c + s4d);
        ps += __shfl_xor(ps, 32);
        l_r += ps;
        // ---- pack P^T B-fragments (T12: cvt_pk + permlane32_swap) ----
        u32 pk0 = cvtpk_bf16(p[0], p[1]),   pk2 = cvtpk_bf16(p[4], p[5]);
        swap_halves(pk0, pk2);
        u32 pk1 = cvtpk_bf16(p[2], p[3]),   pk3 = cvtpk_bf16(p[6], p[7]);
        swap_halves(pk1, pk3);
        u32 pk4 = cvtpk_bf16(p[8], p[9]),   pk6 = cvtpk_bf16(p[12], p[13]);
        swap_halves(pk4, pk6);
        u32 pk5 = cvtpk_bf16(p[10], p[11]), pk7 = cvtpk_bf16(p[14], p[15]);
        swap_halves(pk5, pk7);
        union { u32 u[4]; short8 s8v; } ua, ub;
        ua.u[0] = pk0; ua.u[1] = pk1; ua.u[2] = pk2; ua.u[3] = pk3;
        ub.u[0] = pk4; ub.u[1] = pk5; ub.u[2] = pk6; ub.u[3] = pk7;
        const short8 pa0 = ua.s8v, pa1 = ub.s8v;
        // ---- PV: O^T[d][q] += V^T x P^T (coalesced tiled V loads) ----
#pragma unroll
        for (int db = 0; db < 4; ++db) {
            short8 vf0 = ld8(vtb + ((db * 2)     << 9));
            acco[db] = __builtin_amdgcn_mfma_f32_32x32x16_bf16(vf0, pa0, acco[db], 0, 0, 0);
            short8 vf1 = ld8(vtb + ((db * 2 + 1) << 9));
            acco[db] = __builtin_amdgcn_mfma_f32_32x32x16_bf16(vf1, pa1, acco[db], 0, 0, 0);
        }
    }

    // ---- write partials (bf16, transposed, coalesced over q) ----
    unsigned short* pt = pacc + (size_t)(s * T32 + t32) * 128 * 32;
#pragma unroll
    for (int db = 0; db < 4; ++db)
#pragma unroll
        for (int r = 0; r < 16; ++r) {
            const int dloc = db * 32 + (r & 3) + 8 * (r >> 2) + 4 * hih;
            pt[(size_t)dloc * 32 + l31] = (unsigned short)f2bf(acco[db][r]);
        }
    if (lane < 32) { pm[mlbase + l31] = m_r; pl[mlbase + l31] = l_r; }
}

// ---------------------------------------------------------------------------
// Combine NS bf16 partials per 32-row tile; LDS transpose for coalesced output.
// ---------------------------------------------------------------------------
__global__ __launch_bounds__(256) void combine_kernel(
    const unsigned short* __restrict__ pacc, const float* __restrict__ pm,
    const float* __restrict__ pl, float* __restrict__ out)
{
    __shared__ float wlds[NS][32];
    __shared__ float tlds[128][33];
    const int t32 = blockIdx.x;
    const int tid = threadIdx.x;

    if (tid < 32) {
        const int q = tid;
        float ms[NS], ls[NS];
        float M = -3.0e38f;
#pragma unroll
        for (int s = 0; s < NS; ++s) {
            ms[s] = pm[(size_t)(s * T32 + t32) * 32 + q];
            ls[s] = pl[(size_t)(s * T32 + t32) * 32 + q];
            M = fmaxf(M, ms[s]);
        }
        float w[NS], den = 0.f;
#pragma unroll
        for (int s = 0; s < NS; ++s) { w[s] = __expf(ms[s] - M); den += w[s] * ls[s]; }
        const float inv = 1.f / den;
#pragma unroll
        for (int s = 0; s < NS; ++s) wlds[s][q] = w[s] * inv;
    }
    __syncthreads();

#pragma unroll
    for (int rep = 0; rep < 16; ++rep) {
        const int flat = rep * 256 + tid;
        const int d = flat >> 5, q = flat & 31;
        float acc = 0.f;
#pragma unroll
        for (int s = 0; s < NS; ++s)
            acc += wlds[s][q] *
                   bf2f(pacc[((size_t)(s * T32 + t32) * 128 + d) * 32 + q]);
        tlds[d][q] = acc;
    }
    __syncthreads();

    const size_t row0 = (size_t)t32 * 32;
#pragma unroll
    for (int rep = 0; rep < 16; ++rep) {
        const int flat = rep * 256 + tid;
        const int q = flat >> 7, d = flat & 127;
        out[(row0 + q) * 128 + d] = tlds[d][q];
    }
}

// ---------------------------------------------------------------------------
extern "C" void kernel_launch(void* const* d_in, const int* in_sizes, int n_in,
                              void* d_out, int out_size, void* d_ws, size_t ws_size,
                              hipStream_t stream)
{
    const float* x  = (const float*)d_in[0];
    const float* Wq = (const float*)d_in[1];
    const float* Wk = (const float*)d_in[2];
    const float* Wv = (const float*)d_in[3];
    float* out = (float*)d_out;

    const size_t TBUF = (size_t)BATCH * NT32 * 8 * 512;           // 2M shorts = 4MB

    unsigned short* wbf  = (unsigned short*)d_ws;                 // 384*1024 bf16
    unsigned short* qt   = wbf + (size_t)384 * DMODEL;
    unsigned short* ktb  = qt + TBUF;
    unsigned short* vtl  = ktb + TBUF;
    unsigned short* pacc = vtl + TBUF;                            // 32MB
    float* pm = (float*)(pacc + (size_t)NS * T32 * 128 * 32);
    float* pl = pm + (size_t)NS * T32 * 32;
    // total ~45.3 MB

    const int n8w3 = 3 * HDIM * DMODEL / 8;
    cvt_w_kernel<<<(n8w3 + 255) / 256, 256, 0, stream>>>(Wq, Wk, Wv, wbf);

    qkv_kernel<<<(MROWS / BM) * (384 / BN), 256, 0, stream>>>(x, wbf, qt, ktb, vtl);

    attn_kernel<<<T32 * NS, 64, 0, stream>>>(qt, ktb, vtl, pacc, pm, pl);

    combine_kernel<<<T32, 256, 0, stream>>>(pacc, pm, pl, out);
}

// Round 16
// 108.426 us; speedup vs baseline: 1.1488x; 1.1488x over previous
//
#include <hip/hip_runtime.h>
#include <hip/hip_bf16.h>

#define BATCH  4
#define SEQ    4096
#define DMODEL 1024
#define HDIM   128
#define MROWS  (BATCH * SEQ)   // 16384
#define NT32   (SEQ / 32)      // 128 q-tiles (32 rows) per batch
#define T32    (BATCH * NT32)  // 512
#define NS     8               // KV splits per q-tile (bf16 partials)

// qkv GEMM tile (round-12 proven geometry)
#define BM 64
#define BN 96
#define BK 64
#define KT (DMODEL / BK)       // 16

typedef __attribute__((ext_vector_type(8)))  short short8;
typedef __attribute__((ext_vector_type(4)))  float floatx4;
typedef __attribute__((ext_vector_type(16))) float floatx16;
typedef unsigned int u32;

static __device__ __forceinline__ short f2bf(float f) {
    __hip_bfloat16 h = __float2bfloat16(f);
    union { __hip_bfloat16 h; short s; } u; u.h = h;
    return u.s;
}

static __device__ __forceinline__ float bf2f(unsigned short s) {
    union { u32 u; float f; } v; v.u = ((u32)s) << 16;
    return v.f;
}

static __device__ __forceinline__ short8 ld8(const unsigned short* p) {
    return *reinterpret_cast<const short8*>(p);
}

// async global->LDS, 16 B per lane; LDS dest = wave-uniform base + lane*16.
static __device__ __forceinline__ void gload_lds16(const void* g, void* l) {
    __builtin_amdgcn_global_load_lds(
        (const __attribute__((address_space(1))) unsigned int*)g,
        (__attribute__((address_space(3))) unsigned int*)l,
        16, 0, 0);
}

// pack two f32 -> one u32 of two bf16 (lo = a, hi = b)
static __device__ __forceinline__ u32 cvtpk_bf16(float a, float b) {
    u32 r;
    asm("v_cvt_pk_bf16_f32 %0, %1, %2" : "=v"(r) : "v"(a), "v"(b));
    return r;
}

// a' = {lanes<32: a ; lanes>=32: b from partner(lane-32)}
// b' = {lanes<32: a from partner(lane+32) ; lanes>=32: b}
static __device__ __forceinline__ void swap_halves(u32& a, u32& b) {
#if __has_builtin(__builtin_amdgcn_permlane32_swap)
    typedef __attribute__((ext_vector_type(2))) int int2v;
    int2v r = __builtin_amdgcn_permlane32_swap((int)a, (int)b, false, false);
    a = (u32)r[0]; b = (u32)r[1];
#else
    u32 ap = (u32)__shfl_xor((int)a, 32);
    u32 bp = (u32)__shfl_xor((int)b, 32);
    const bool hih = (threadIdx.x & 32) != 0;
    u32 na = hih ? bp : a;
    u32 nb = hih ? b : ap;
    a = na; b = nb;
#endif
}

// ===========================================================================
// FRAGMENT-TILED LAYOUTS (round-12 proven — attn loads are 1KB coalesced):
//  qt/kt: (b,s,d) at ((b*NT32+s/32)*8 + d/16)*512 + ((d/8)%2*32 + s%32)*8 + d%8
//  vtl:   (b,s,d) at ((b*NT32+s/32)*8 + (d/32)*2 + (s%32)/16)*512
//                     + ((s/8)%2*32 + d%32)*8 + s%8
// ===========================================================================

// ---------------------------------------------------------------------------
// W = [Wq;Wk;Wv] fp32 -> bf16, Wq pre-scaled by 1/sqrt(H). One launch.
// ---------------------------------------------------------------------------
__global__ __launch_bounds__(256) void cvt_w_kernel(
    const float* __restrict__ Wq, const float* __restrict__ Wk,
    const float* __restrict__ Wv, unsigned short* __restrict__ wbf)
{
    const int n8w = HDIM * DMODEL / 8;                // 16384
    int i = blockIdx.x * 256 + threadIdx.x;
    if (i >= 3 * n8w) return;
    const int which = i / n8w;
    const int j = i - which * n8w;
    const float* src = (which == 0) ? Wq : (which == 1) ? Wk : Wv;
    const float scale = (which == 0) ? 0.08838834764831845f : 1.0f;
    const float4* s4 = reinterpret_cast<const float4*>(src);
    float4 a = s4[2 * j];
    float4 b = s4[2 * j + 1];
    short8 o;
    o[0] = f2bf(a.x * scale); o[1] = f2bf(a.y * scale);
    o[2] = f2bf(a.z * scale); o[3] = f2bf(a.w * scale);
    o[4] = f2bf(b.x * scale); o[5] = f2bf(b.y * scale);
    o[6] = f2bf(b.z * scale); o[7] = f2bf(b.w * scale);
    reinterpret_cast<short8*>(wbf)[i] = o;
}

// ---------------------------------------------------------------------------
// QKV projection, double-buffered LDS GEMM (round-12 proven loop, BM=64).
// NEW EPILOGUE: block's 12KB output staged in LDS as an image of the 12
// destination 1KB fragment-blocks, then copied out with 16B-coalesced
// short8 stores (3/thread) — replaces 24 scattered 2-byte global
// stores/thread (the store-transaction scatter that was invariant across
// all prior qkv variants).
// ---------------------------------------------------------------------------
__global__ __launch_bounds__(256, 4) void qkv_kernel(
    const float* __restrict__ x,             // [MROWS][DMODEL] fp32
    const unsigned short* __restrict__ wbf,  // [384][DMODEL] bf16
    unsigned short* __restrict__ qt,         // tiled Q
    unsigned short* __restrict__ kt,         // tiled K
    unsigned short* __restrict__ vtl)        // tiled V
{
    __shared__ __align__(16) unsigned short A_lds[2][BM][BK];  // 16 KB
    __shared__ __align__(16) unsigned short B_lds[2][BN][BK];  // 24 KB

    const int raw  = blockIdx.x;
    const int vid  = (raw & 7) * 128 + (raw >> 3);
    const int mblk = vid >> 2;
    const int nblk = vid & 3;
    const int m0   = mblk * BM;
    const int n0   = nblk * BN;

    const int tid  = threadIdx.x;
    const int wv   = tid >> 6;
    const int lane = tid & 63;
    const int lr   = lane & 15;
    const int lh   = lane >> 4;
    const int wm   = wv >> 1;   // 0/1 -> M offset 0/32
    const int wn   = wv & 1;    // 0/1 -> N offset 0/48

    // A staging: thread -> row ar, quarter aq (16 floats -> 2 swizzled short8)
    const int ar = tid >> 2;
    const int aq = tid & 3;
    const float* asrc = x + (size_t)(m0 + ar) * DMODEL + aq * 16;

    // B staging: lane -> row rbase+(lane>>3); source unit pre-swizzled
    const int brow  = lane >> 3;
    const int bunit = (lane & 7) ^ brow;

    floatx4 acc[2][3];
#pragma unroll
    for (int mf = 0; mf < 2; ++mf)
#pragma unroll
        for (int nf = 0; nf < 3; ++nf) acc[mf][nf] = (floatx4){0.f, 0.f, 0.f, 0.f};

    // ---- prologue: stage tile 0 into buffer 0 ----
    {
#pragma unroll
        for (int j = 0; j < 3; ++j) {
            const int rbase = (j * 4 + wv) * 8;
            gload_lds16(wbf + (size_t)(n0 + rbase + brow) * DMODEL + bunit * 8,
                        &B_lds[0][rbase][0]);
        }
        float4 f0 = *reinterpret_cast<const float4*>(asrc);
        float4 f1 = *reinterpret_cast<const float4*>(asrc + 4);
        float4 f2 = *reinterpret_cast<const float4*>(asrc + 8);
        float4 f3 = *reinterpret_cast<const float4*>(asrc + 12);
        short8 v0, v1;
        v0[0] = f2bf(f0.x); v0[1] = f2bf(f0.y); v0[2] = f2bf(f0.z); v0[3] = f2bf(f0.w);
        v0[4] = f2bf(f1.x); v0[5] = f2bf(f1.y); v0[6] = f2bf(f1.z); v0[7] = f2bf(f1.w);
        v1[0] = f2bf(f2.x); v1[1] = f2bf(f2.y); v1[2] = f2bf(f2.z); v1[3] = f2bf(f2.w);
        v1[4] = f2bf(f3.x); v1[5] = f2bf(f3.y); v1[6] = f2bf(f3.z); v1[7] = f2bf(f3.w);
        const int u0 = (2 * aq)     ^ (ar & 7);
        const int u1 = (2 * aq + 1) ^ (ar & 7);
        *reinterpret_cast<short8*>(&A_lds[0][ar][u0 * 8]) = v0;
        *reinterpret_cast<short8*>(&A_lds[0][ar][u1 * 8]) = v1;
    }
    __syncthreads();

    for (int ktile = 0; ktile < KT; ++ktile) {
        const int cur = ktile & 1;
        const int nxt = cur ^ 1;
        float4 f0, f1, f2, f3;
        if (ktile + 1 < KT) {
#pragma unroll
            for (int j = 0; j < 3; ++j) {
                const int rbase = (j * 4 + wv) * 8;
                gload_lds16(wbf + (size_t)(n0 + rbase + brow) * DMODEL
                                + (ktile + 1) * BK + bunit * 8,
                            &B_lds[nxt][rbase][0]);
            }
            const float* a = asrc + (ktile + 1) * BK;
            f0 = *reinterpret_cast<const float4*>(a);
            f1 = *reinterpret_cast<const float4*>(a + 4);
            f2 = *reinterpret_cast<const float4*>(a + 8);
            f3 = *reinterpret_cast<const float4*>(a + 12);
        }
#pragma unroll
        for (int kk = 0; kk < 2; ++kk) {
            const int uswz = (kk * 4 + lh) ^ (lr & 7);
            short8 af[2], bfr[3];
#pragma unroll
            for (int mf = 0; mf < 2; ++mf)
                af[mf] = ld8(&A_lds[cur][wm * 32 + mf * 16 + lr][uswz * 8]);
#pragma unroll
            for (int nf = 0; nf < 3; ++nf)
                bfr[nf] = ld8(&B_lds[cur][wn * 48 + nf * 16 + lr][uswz * 8]);
#pragma unroll
            for (int mf = 0; mf < 2; ++mf)
#pragma unroll
                for (int nf = 0; nf < 3; ++nf)
                    acc[mf][nf] = __builtin_amdgcn_mfma_f32_16x16x32_bf16(
                        af[mf], bfr[nf], acc[mf][nf], 0, 0, 0);
        }
        if (ktile + 1 < KT) {
            short8 v0, v1;
            v0[0] = f2bf(f0.x); v0[1] = f2bf(f0.y); v0[2] = f2bf(f0.z); v0[3] = f2bf(f0.w);
            v0[4] = f2bf(f1.x); v0[5] = f2bf(f1.y); v0[6] = f2bf(f1.z); v0[7] = f2bf(f1.w);
            v1[0] = f2bf(f2.x); v1[1] = f2bf(f2.y); v1[2] = f2bf(f2.z); v1[3] = f2bf(f2.w);
            v1[4] = f2bf(f3.x); v1[5] = f2bf(f3.y); v1[6] = f2bf(f3.z); v1[7] = f2bf(f3.w);
            const int u0 = (2 * aq)     ^ (ar & 7);
            const int u1 = (2 * aq + 1) ^ (ar & 7);
            *reinterpret_cast<short8*>(&A_lds[nxt][ar][u0 * 8]) = v0;
            *reinterpret_cast<short8*>(&A_lds[nxt][ar][u1 * 8]) = v1;
        }
        __syncthreads();
    }

    // ======== NEW epilogue: LDS-staged, coalesced copy-out ========
    // Block output = 64 rows (2 s-tiles: st=wm) x 96 cols = 12 x 1KB
    // fragment-blocks. Local id lf = st*6 + li (li per nblk below).
    __syncthreads();                       // A_lds free for reuse
    unsigned short* out_l = &A_lds[0][0][0];   // 12KB image (16KB avail)

    const int t0 = (m0 & (SEQ - 1)) >> 5;  // first 32-tile (no batch straddle)
    const int bb = m0 >> 12;
    const int st = wm;

#pragma unroll
    for (int nf = 0; nf < 3; ++nf) {
        const int cl = wn * 48 + nf * 16 + lr;   // 0..95 local col
#pragma unroll
        for (int mf = 0; mf < 2; ++mf) {
#pragma unroll
            for (int r = 0; r < 4; ++r) {
                const int srow = mf * 16 + lh * 4 + r;   // 0..31 within s-tile
                const unsigned short vv = (unsigned short)f2bf(acc[mf][nf][r]);
                int lf, off;
                if (nblk == 0) {                       // qt d=cl (frags 0..5)
                    lf  = st * 6 + (cl >> 4);
                    off = ((cl >> 3) & 1) * 256 + srow * 8 + (cl & 7);
                } else if (nblk == 1) {                // qt f6..7 | kt f0..3
                    lf  = (cl < 32) ? st * 6 + (cl >> 4)
                                    : st * 6 + 2 + ((cl - 32) >> 4);
                    off = ((cl >> 3) & 1) * 256 + srow * 8 + (cl & 7);
                } else if (nblk == 2) {                // kt f4..7 | vtl g0
                    if (cl < 64) {
                        lf  = st * 6 + (cl >> 4);
                        off = ((cl >> 3) & 1) * 256 + srow * 8 + (cl & 7);
                    } else {
                        const int dg = cl - 64;        // 0..31
                        lf  = st * 6 + 4 + ((srow >> 4) & 1);
                        off = ((srow >> 3) & 1) * 256 + dg * 8 + (srow & 7);
                    }
                } else {                               // vtl g1..3
                    const int d = cl + 32;             // 32..127
                    lf  = st * 6 + ((d >> 5) - 1) * 2 + ((srow >> 4) & 1);
                    off = ((srow >> 3) & 1) * 256 + (d & 31) * 8 + (srow & 7);
                }
                out_l[lf * 512 + off] = vv;
            }
        }
    }
    __syncthreads();

    // coalesced copy-out: 12 fragblocks x 64 short8 units = 768; 3/thread
#pragma unroll
    for (int k = 0; k < 3; ++k) {
        const int u   = tid + 256 * k;       // 0..767
        const int fb  = u >> 6;              // 0..11
        const int iu  = u & 63;
        const int fst = (fb >= 6) ? 1 : 0;
        const int li  = fb - 6 * fst;
        const size_t tb8 = (size_t)((bb * NT32 + t0 + fst) * 8);
        unsigned short* gbase;
        if (nblk == 0) {
            gbase = qt + ((tb8 + li) << 9);
        } else if (nblk == 1) {
            gbase = (li < 2) ? qt  + ((tb8 + 6 + li) << 9)
                             : kt  + ((tb8 + (li - 2)) << 9);
        } else if (nblk == 2) {
            gbase = (li < 4) ? kt  + ((tb8 + 4 + li) << 9)
                             : vtl + ((tb8 + (li - 4)) << 9);   // g0*2+sub
        } else {
            gbase = vtl + ((tb8 + 2 + li) << 9);   // (1+(li>>1))*2+(li&1)=2+li
        }
        *reinterpret_cast<short8*>(gbase + iu * 8) =
            *reinterpret_cast<const short8*>(&out_l[fb * 512 + iu * 8]);
    }
}

// ---------------------------------------------------------------------------
// Causal flash attention — round-12 proven (fragment-tiled coalesced loads).
// ---------------------------------------------------------------------------
__global__ __launch_bounds__(64) void attn_kernel(
    const unsigned short* __restrict__ qt,
    const unsigned short* __restrict__ kt,
    const unsigned short* __restrict__ vtl,
    unsigned short* __restrict__ pacc,   // [NS][T32][128][32] bf16
    float* __restrict__ pm,
    float* __restrict__ pl)
{
    const int bid  = blockIdx.x;
    const int xcd  = bid & 7;
    const int b    = xcd >> 1;                // batch <-> XCD pair
    const int par  = xcd & 1;
    const int idx  = bid >> 3;                // 0..511 within XCD
    const int s    = idx & 7;                 // split
    const int trk  = idx >> 3;                // 0..63 tile-rank on this XCD
    const int t32b = (NT32 - 1) - (trk * 2 + par);   // longest first
    const int q0   = t32b * 32;
    const int t32  = b * NT32 + t32b;
    const int lane = threadIdx.x & 63;
    const int l31  = lane & 31;
    const int hih  = lane >> 5;

    const int nkv   = q0 + 32;
    const int chunk = ((nkv + NS * 32 - 1) / (NS * 32)) * 32;
    const int lo    = s * chunk;
    const int hikv  = (lo + chunk < nkv) ? lo + chunk : nkv;
    const size_t mlbase = (size_t)(s * T32 + t32) * 32;

    if (lo >= hikv) {
        if (lane < 32) { pm[mlbase + l31] = -3.0e38f; pl[mlbase + l31] = 0.f; }
        return;
    }

    // Q fragments (coalesced tiled loads)
    const unsigned short* qtb =
        qt + ((size_t)((b * NT32 + t32b) * 8) << 9) + lane * 8;
    short8 qa[8];
#pragma unroll
    for (int ks = 0; ks < 8; ++ks) qa[ks] = ld8(qtb + (ks << 9));

    floatx16 acco[4];
#pragma unroll
    for (int db = 0; db < 4; ++db)
#pragma unroll
        for (int i = 0; i < 16; ++i) acco[db][i] = 0.f;
    float m_r = -3.0e38f, l_r = 0.f;

    for (int kv0 = lo; kv0 < hikv; kv0 += 32) {
        const int t = kv0 >> 5;
        const unsigned short* ktb =
            kt + ((size_t)((b * NT32 + t) * 8) << 9) + lane * 8;
        const unsigned short* vtb =
            vtl + ((size_t)((b * NT32 + t) * 8) << 9) + lane * 8;

        // ---- scores S^T[kv][q] = mfma(K, Q) ----
        floatx16 sc;
#pragma unroll
        for (int i = 0; i < 16; ++i) sc[i] = 0.f;
#pragma unroll
        for (int ks = 0; ks < 8; ++ks) {
            short8 kf = ld8(ktb + (ks << 9));
            sc = __builtin_amdgcn_mfma_f32_32x32x16_bf16(kf, qa[ks], sc, 0, 0, 0);
        }
        // ---- causal mask: only the diagonal tile ----
        if (kv0 == q0) {
#pragma unroll
            for (int r = 0; r < 16; ++r) {
                const int kvloc = (r & 3) + 8 * (r >> 2) + 4 * hih;
                if (kvloc > l31) sc[r] = -3.0e38f;
            }
        }
        // ---- lane-local max (tree) + cross-half ----
        float t8[8];
#pragma unroll
        for (int i = 0; i < 8; ++i) t8[i] = fmaxf(sc[i], sc[i + 8]);
        float t4a = fmaxf(t8[0], t8[4]), t4b = fmaxf(t8[1], t8[5]);
        float t4c = fmaxf(t8[2], t8[6]), t4d = fmaxf(t8[3], t8[7]);
        float pmax = fmaxf(fmaxf(t4a, t4b), fmaxf(t4c, t4d));
        pmax = fmaxf(pmax, __shfl_xor(pmax, 32));
        // ---- deferred rescale (T13, THR=8) ----
        if (__any(pmax > m_r + 8.f)) {
            const float mn  = fmaxf(m_r, pmax);
            const float fac = __expf(m_r - mn);
            m_r = mn; l_r *= fac;
#pragma unroll
            for (int db = 0; db < 4; ++db)
#pragma unroll
                for (int i = 0; i < 16; ++i) acco[db][i] *= fac;
        }
        // ---- p = exp(s - m), lane-local sum ----
        float p[16];
#pragma unroll
        for (int r = 0; r < 16; ++r) p[r] = __expf(sc[r] - m_r);
        float s8[8];
#pragma unroll
        for (int i = 0; i < 8; ++i) s8[i] = p[i] + p[i + 8];
        float s4a = s8[0] + s8[4], s4b = s8[1] + s8[5];
        float s4c = s8[2] + s8[6], s4d = s8[3] + s8[7];
        float ps = (s4a + s4b) + (s4c + s4d);
        ps += __shfl_xor(ps, 32);
        l_r += ps;
        // ---- pack P^T B-fragments (T12: cvt_pk + permlane32_swap) ----
        u32 pk0 = cvtpk_bf16(p[0], p[1]),   pk2 = cvtpk_bf16(p[4], p[5]);
        swap_halves(pk0, pk2);
        u32 pk1 = cvtpk_bf16(p[2], p[3]),   pk3 = cvtpk_bf16(p[6], p[7]);
        swap_halves(pk1, pk3);
        u32 pk4 = cvtpk_bf16(p[8], p[9]),   pk6 = cvtpk_bf16(p[12], p[13]);
        swap_halves(pk4, pk6);
        u32 pk5 = cvtpk_bf16(p[10], p[11]), pk7 = cvtpk_bf16(p[14], p[15]);
        swap_halves(pk5, pk7);
        union { u32 u[4]; short8 s8v; } ua, ub;
        ua.u[0] = pk0; ua.u[1] = pk1; ua.u[2] = pk2; ua.u[3] = pk3;
        ub.u[0] = pk4; ub.u[1] = pk5; ub.u[2] = pk6; ub.u[3] = pk7;
        const short8 pa0 = ua.s8v, pa1 = ub.s8v;
        // ---- PV: O^T[d][q] += V^T x P^T (coalesced tiled V loads) ----
#pragma unroll
        for (int db = 0; db < 4; ++db) {
            short8 vf0 = ld8(vtb + ((db * 2)     << 9));
            acco[db] = __builtin_amdgcn_mfma_f32_32x32x16_bf16(vf0, pa0, acco[db], 0, 0, 0);
            short8 vf1 = ld8(vtb + ((db * 2 + 1) << 9));
            acco[db] = __builtin_amdgcn_mfma_f32_32x32x16_bf16(vf1, pa1, acco[db], 0, 0, 0);
        }
    }

    // ---- write partials (bf16, transposed, coalesced over q) ----
    unsigned short* pt = pacc + (size_t)(s * T32 + t32) * 128 * 32;
#pragma unroll
    for (int db = 0; db < 4; ++db)
#pragma unroll
        for (int r = 0; r < 16; ++r) {
            const int dloc = db * 32 + (r & 3) + 8 * (r >> 2) + 4 * hih;
            pt[(size_t)dloc * 32 + l31] = (unsigned short)f2bf(acco[db][r]);
        }
    if (lane < 32) { pm[mlbase + l31] = m_r; pl[mlbase + l31] = l_r; }
}

// ---------------------------------------------------------------------------
// Combine NS bf16 partials per 32-row tile; LDS transpose for coalesced output.
// ---------------------------------------------------------------------------
__global__ __launch_bounds__(256) void combine_kernel(
    const unsigned short* __restrict__ pacc, const float* __restrict__ pm,
    const float* __restrict__ pl, float* __restrict__ out)
{
    __shared__ float wlds[NS][32];
    __shared__ float tlds[128][33];
    const int t32 = blockIdx.x;
    const int tid = threadIdx.x;

    if (tid < 32) {
        const int q = tid;
        float ms[NS], ls[NS];
        float M = -3.0e38f;
#pragma unroll
        for (int s = 0; s < NS; ++s) {
            ms[s] = pm[(size_t)(s * T32 + t32) * 32 + q];
            ls[s] = pl[(size_t)(s * T32 + t32) * 32 + q];
            M = fmaxf(M, ms[s]);
        }
        float w[NS], den = 0.f;
#pragma unroll
        for (int s = 0; s < NS; ++s) { w[s] = __expf(ms[s] - M); den += w[s] * ls[s]; }
        const float inv = 1.f / den;
#pragma unroll
        for (int s = 0; s < NS; ++s) wlds[s][q] = w[s] * inv;
    }
    __syncthreads();

#pragma unroll
    for (int rep = 0; rep < 16; ++rep) {
        const int flat = rep * 256 + tid;
        const int d = flat >> 5, q = flat & 31;
        float acc = 0.f;
#pragma unroll
        for (int s = 0; s < NS; ++s)
            acc += wlds[s][q] *
                   bf2f(pacc[((size_t)(s * T32 + t32) * 128 + d) * 32 + q]);
        tlds[d][q] = acc;
    }
    __syncthreads();

    const size_t row0 = (size_t)t32 * 32;
#pragma unroll
    for (int rep = 0; rep < 16; ++rep) {
        const int flat = rep * 256 + tid;
        const int q = flat >> 7, d = flat & 127;
        out[(row0 + q) * 128 + d] = tlds[d][q];
    }
}

// ---------------------------------------------------------------------------
extern "C" void kernel_launch(void* const* d_in, const int* in_sizes, int n_in,
                              void* d_out, int out_size, void* d_ws, size_t ws_size,
                              hipStream_t stream)
{
    const float* x  = (const float*)d_in[0];
    const float* Wq = (const float*)d_in[1];
    const float* Wk = (const float*)d_in[2];
    const float* Wv = (const float*)d_in[3];
    float* out = (float*)d_out;

    const size_t TBUF = (size_t)BATCH * NT32 * 8 * 512;           // 2M shorts = 4MB

    unsigned short* wbf  = (unsigned short*)d_ws;                 // 384*1024 bf16
    unsigned short* qt   = wbf + (size_t)384 * DMODEL;
    unsigned short* ktb  = qt + TBUF;
    unsigned short* vtl  = ktb + TBUF;
    unsigned short* pacc = vtl + TBUF;                            // 32MB
    float* pm = (float*)(pacc + (size_t)NS * T32 * 128 * 32);
    float* pl = pm + (size_t)NS * T32 * 32;
    // total ~45.3 MB

    const int n8w3 = 3 * HDIM * DMODEL / 8;
    cvt_w_kernel<<<(n8w3 + 255) / 256, 256, 0, stream>>>(Wq, Wk, Wv, wbf);

    qkv_kernel<<<(MROWS / BM) * (384 / BN), 256, 0, stream>>>(x, wbf, qt, ktb, vtl);

    attn_kernel<<<T32 * NS, 64, 0, stream>>>(qt, ktb, vtl, pacc, pm, pl);

    combine_kernel<<<T32, 256, 0, stream>>>(pacc, pm, pl, out);
}

// Round 17
// 101.282 us; speedup vs baseline: 1.2298x; 1.0705x over previous
//
#include <hip/hip_runtime.h>
#include <hip/hip_bf16.h>

#define BATCH  4
#define SEQ    4096
#define DMODEL 1024
#define HDIM   128
#define MROWS  (BATCH * SEQ)   // 16384
#define NT32   (SEQ / 32)      // 128 q-tiles (32 rows) per batch
#define T32    (BATCH * NT32)  // 512
#define NS     4               // KV splits per q-tile (bf16 partials)

// qkv GEMM tile (round-12/16 proven geometry)
#define BM 64
#define BN 96
#define BK 64
#define KT (DMODEL / BK)       // 16

typedef __attribute__((ext_vector_type(8)))  short short8;
typedef __attribute__((ext_vector_type(4)))  float floatx4;
typedef __attribute__((ext_vector_type(16))) float floatx16;
typedef unsigned int u32;

static __device__ __forceinline__ short f2bf(float f) {
    __hip_bfloat16 h = __float2bfloat16(f);
    union { __hip_bfloat16 h; short s; } u; u.h = h;
    return u.s;
}

static __device__ __forceinline__ float bf2f(unsigned short s) {
    union { u32 u; float f; } v; v.u = ((u32)s) << 16;
    return v.f;
}

static __device__ __forceinline__ short8 ld8(const unsigned short* p) {
    return *reinterpret_cast<const short8*>(p);
}

// async global->LDS, 16 B per lane; LDS dest = wave-uniform base + lane*16.
static __device__ __forceinline__ void gload_lds16(const void* g, void* l) {
    __builtin_amdgcn_global_load_lds(
        (const __attribute__((address_space(1))) unsigned int*)g,
        (__attribute__((address_space(3))) unsigned int*)l,
        16, 0, 0);
}

// pack two f32 -> one u32 of two bf16 (lo = a, hi = b)
static __device__ __forceinline__ u32 cvtpk_bf16(float a, float b) {
    u32 r;
    asm("v_cvt_pk_bf16_f32 %0, %1, %2" : "=v"(r) : "v"(a), "v"(b));
    return r;
}

// a' = {lanes<32: a ; lanes>=32: b from partner(lane-32)}
// b' = {lanes<32: a from partner(lane+32) ; lanes>=32: b}
static __device__ __forceinline__ void swap_halves(u32& a, u32& b) {
#if __has_builtin(__builtin_amdgcn_permlane32_swap)
    typedef __attribute__((ext_vector_type(2))) int int2v;
    int2v r = __builtin_amdgcn_permlane32_swap((int)a, (int)b, false, false);
    a = (u32)r[0]; b = (u32)r[1];
#else
    u32 ap = (u32)__shfl_xor((int)a, 32);
    u32 bp = (u32)__shfl_xor((int)b, 32);
    const bool hih = (threadIdx.x & 32) != 0;
    u32 na = hih ? bp : a;
    u32 nb = hih ? b : ap;
    a = na; b = nb;
#endif
}

// ===========================================================================
// FRAGMENT-TILED LAYOUTS (round-12 proven — attn loads are 1KB coalesced):
//  qt/kt: (b,s,d) at ((b*NT32+s/32)*8 + d/16)*512 + ((d/8)%2*32 + s%32)*8 + d%8
//  vtl:   (b,s,d) at ((b*NT32+s/32)*8 + (d/32)*2 + (s%32)/16)*512
//                     + ((s/8)%2*32 + d%32)*8 + s%8
// ===========================================================================

// ---------------------------------------------------------------------------
// W = [Wq;Wk;Wv] fp32 -> bf16, Wq pre-scaled by 1/sqrt(H). One launch.
// ---------------------------------------------------------------------------
__global__ __launch_bounds__(256) void cvt_w_kernel(
    const float* __restrict__ Wq, const float* __restrict__ Wk,
    const float* __restrict__ Wv, unsigned short* __restrict__ wbf)
{
    const int n8w = HDIM * DMODEL / 8;                // 16384
    int i = blockIdx.x * 256 + threadIdx.x;
    if (i >= 3 * n8w) return;
    const int which = i / n8w;
    const int j = i - which * n8w;
    const float* src = (which == 0) ? Wq : (which == 1) ? Wk : Wv;
    const float scale = (which == 0) ? 0.08838834764831845f : 1.0f;
    const float4* s4 = reinterpret_cast<const float4*>(src);
    float4 a = s4[2 * j];
    float4 b = s4[2 * j + 1];
    short8 o;
    o[0] = f2bf(a.x * scale); o[1] = f2bf(a.y * scale);
    o[2] = f2bf(a.z * scale); o[3] = f2bf(a.w * scale);
    o[4] = f2bf(b.x * scale); o[5] = f2bf(b.y * scale);
    o[6] = f2bf(b.z * scale); o[7] = f2bf(b.w * scale);
    reinterpret_cast<short8*>(wbf)[i] = o;
}

// ---------------------------------------------------------------------------
// QKV projection, double-buffered LDS GEMM (round-16 proven, unchanged).
// ---------------------------------------------------------------------------
__global__ __launch_bounds__(256, 4) void qkv_kernel(
    const float* __restrict__ x,             // [MROWS][DMODEL] fp32
    const unsigned short* __restrict__ wbf,  // [384][DMODEL] bf16
    unsigned short* __restrict__ qt,         // tiled Q
    unsigned short* __restrict__ kt,         // tiled K
    unsigned short* __restrict__ vtl)        // tiled V
{
    __shared__ __align__(16) unsigned short A_lds[2][BM][BK];  // 16 KB
    __shared__ __align__(16) unsigned short B_lds[2][BN][BK];  // 24 KB

    const int raw  = blockIdx.x;
    const int vid  = (raw & 7) * 128 + (raw >> 3);
    const int mblk = vid >> 2;
    const int nblk = vid & 3;
    const int m0   = mblk * BM;
    const int n0   = nblk * BN;

    const int tid  = threadIdx.x;
    const int wv   = tid >> 6;
    const int lane = tid & 63;
    const int lr   = lane & 15;
    const int lh   = lane >> 4;
    const int wm   = wv >> 1;   // 0/1 -> M offset 0/32
    const int wn   = wv & 1;    // 0/1 -> N offset 0/48

    const int ar = tid >> 2;
    const int aq = tid & 3;
    const float* asrc = x + (size_t)(m0 + ar) * DMODEL + aq * 16;

    const int brow  = lane >> 3;
    const int bunit = (lane & 7) ^ brow;

    floatx4 acc[2][3];
#pragma unroll
    for (int mf = 0; mf < 2; ++mf)
#pragma unroll
        for (int nf = 0; nf < 3; ++nf) acc[mf][nf] = (floatx4){0.f, 0.f, 0.f, 0.f};

    // ---- prologue: stage tile 0 into buffer 0 ----
    {
#pragma unroll
        for (int j = 0; j < 3; ++j) {
            const int rbase = (j * 4 + wv) * 8;
            gload_lds16(wbf + (size_t)(n0 + rbase + brow) * DMODEL + bunit * 8,
                        &B_lds[0][rbase][0]);
        }
        float4 f0 = *reinterpret_cast<const float4*>(asrc);
        float4 f1 = *reinterpret_cast<const float4*>(asrc + 4);
        float4 f2 = *reinterpret_cast<const float4*>(asrc + 8);
        float4 f3 = *reinterpret_cast<const float4*>(asrc + 12);
        short8 v0, v1;
        v0[0] = f2bf(f0.x); v0[1] = f2bf(f0.y); v0[2] = f2bf(f0.z); v0[3] = f2bf(f0.w);
        v0[4] = f2bf(f1.x); v0[5] = f2bf(f1.y); v0[6] = f2bf(f1.z); v0[7] = f2bf(f1.w);
        v1[0] = f2bf(f2.x); v1[1] = f2bf(f2.y); v1[2] = f2bf(f2.z); v1[3] = f2bf(f2.w);
        v1[4] = f2bf(f3.x); v1[5] = f2bf(f3.y); v1[6] = f2bf(f3.z); v1[7] = f2bf(f3.w);
        const int u0 = (2 * aq)     ^ (ar & 7);
        const int u1 = (2 * aq + 1) ^ (ar & 7);
        *reinterpret_cast<short8*>(&A_lds[0][ar][u0 * 8]) = v0;
        *reinterpret_cast<short8*>(&A_lds[0][ar][u1 * 8]) = v1;
    }
    __syncthreads();

    for (int ktile = 0; ktile < KT; ++ktile) {
        const int cur = ktile & 1;
        const int nxt = cur ^ 1;
        float4 f0, f1, f2, f3;
        if (ktile + 1 < KT) {
#pragma unroll
            for (int j = 0; j < 3; ++j) {
                const int rbase = (j * 4 + wv) * 8;
                gload_lds16(wbf + (size_t)(n0 + rbase + brow) * DMODEL
                                + (ktile + 1) * BK + bunit * 8,
                            &B_lds[nxt][rbase][0]);
            }
            const float* a = asrc + (ktile + 1) * BK;
            f0 = *reinterpret_cast<const float4*>(a);
            f1 = *reinterpret_cast<const float4*>(a + 4);
            f2 = *reinterpret_cast<const float4*>(a + 8);
            f3 = *reinterpret_cast<const float4*>(a + 12);
        }
#pragma unroll
        for (int kk = 0; kk < 2; ++kk) {
            const int uswz = (kk * 4 + lh) ^ (lr & 7);
            short8 af[2], bfr[3];
#pragma unroll
            for (int mf = 0; mf < 2; ++mf)
                af[mf] = ld8(&A_lds[cur][wm * 32 + mf * 16 + lr][uswz * 8]);
#pragma unroll
            for (int nf = 0; nf < 3; ++nf)
                bfr[nf] = ld8(&B_lds[cur][wn * 48 + nf * 16 + lr][uswz * 8]);
#pragma unroll
            for (int mf = 0; mf < 2; ++mf)
#pragma unroll
                for (int nf = 0; nf < 3; ++nf)
                    acc[mf][nf] = __builtin_amdgcn_mfma_f32_16x16x32_bf16(
                        af[mf], bfr[nf], acc[mf][nf], 0, 0, 0);
        }
        if (ktile + 1 < KT) {
            short8 v0, v1;
            v0[0] = f2bf(f0.x); v0[1] = f2bf(f0.y); v0[2] = f2bf(f0.z); v0[3] = f2bf(f0.w);
            v0[4] = f2bf(f1.x); v0[5] = f2bf(f1.y); v0[6] = f2bf(f1.z); v0[7] = f2bf(f1.w);
            v1[0] = f2bf(f2.x); v1[1] = f2bf(f2.y); v1[2] = f2bf(f2.z); v1[3] = f2bf(f2.w);
            v1[4] = f2bf(f3.x); v1[5] = f2bf(f3.y); v1[6] = f2bf(f3.z); v1[7] = f2bf(f3.w);
            const int u0 = (2 * aq)     ^ (ar & 7);
            const int u1 = (2 * aq + 1) ^ (ar & 7);
            *reinterpret_cast<short8*>(&A_lds[nxt][ar][u0 * 8]) = v0;
            *reinterpret_cast<short8*>(&A_lds[nxt][ar][u1 * 8]) = v1;
        }
        __syncthreads();
    }

    // ======== epilogue: LDS-staged, coalesced copy-out (round-16 proven) ====
    __syncthreads();
    unsigned short* out_l = &A_lds[0][0][0];   // 12KB image

    const int t0 = (m0 & (SEQ - 1)) >> 5;
    const int bb = m0 >> 12;
    const int st = wm;

#pragma unroll
    for (int nf = 0; nf < 3; ++nf) {
        const int cl = wn * 48 + nf * 16 + lr;
#pragma unroll
        for (int mf = 0; mf < 2; ++mf) {
#pragma unroll
            for (int r = 0; r < 4; ++r) {
                const int srow = mf * 16 + lh * 4 + r;
                const unsigned short vv = (unsigned short)f2bf(acc[mf][nf][r]);
                int lf, off;
                if (nblk == 0) {
                    lf  = st * 6 + (cl >> 4);
                    off = ((cl >> 3) & 1) * 256 + srow * 8 + (cl & 7);
                } else if (nblk == 1) {
                    lf  = (cl < 32) ? st * 6 + (cl >> 4)
                                    : st * 6 + 2 + ((cl - 32) >> 4);
                    off = ((cl >> 3) & 1) * 256 + srow * 8 + (cl & 7);
                } else if (nblk == 2) {
                    if (cl < 64) {
                        lf  = st * 6 + (cl >> 4);
                        off = ((cl >> 3) & 1) * 256 + srow * 8 + (cl & 7);
                    } else {
                        const int dg = cl - 64;
                        lf  = st * 6 + 4 + ((srow >> 4) & 1);
                        off = ((srow >> 3) & 1) * 256 + dg * 8 + (srow & 7);
                    }
                } else {
                    const int d = cl + 32;
                    lf  = st * 6 + ((d >> 5) - 1) * 2 + ((srow >> 4) & 1);
                    off = ((srow >> 3) & 1) * 256 + (d & 31) * 8 + (srow & 7);
                }
                out_l[lf * 512 + off] = vv;
            }
        }
    }
    __syncthreads();

#pragma unroll
    for (int k = 0; k < 3; ++k) {
        const int u   = tid + 256 * k;
        const int fb  = u >> 6;
        const int iu  = u & 63;
        const int fst = (fb >= 6) ? 1 : 0;
        const int li  = fb - 6 * fst;
        const size_t tb8 = (size_t)((bb * NT32 + t0 + fst) * 8);
        unsigned short* gbase;
        if (nblk == 0) {
            gbase = qt + ((tb8 + li) << 9);
        } else if (nblk == 1) {
            gbase = (li < 2) ? qt  + ((tb8 + 6 + li) << 9)
                             : kt  + ((tb8 + (li - 2)) << 9);
        } else if (nblk == 2) {
            gbase = (li < 4) ? kt  + ((tb8 + 4 + li) << 9)
                             : vtl + ((tb8 + (li - 4)) << 9);
        } else {
            gbase = vtl + ((tb8 + 2 + li) << 9);
        }
        *reinterpret_cast<short8*>(gbase + iu * 8) =
            *reinterpret_cast<const short8*>(&out_l[fb * 512 + iu * 8]);
    }
}

// ---------------------------------------------------------------------------
// Causal flash attention — round-12 proven structure; NS=4 (grid 2048).
// Decode: xcd=bid&7 (b=xcd>>1, par=xcd&1); idx=bid>>3 in 0..255;
// s=idx&3 (split), trk=idx>>2 (0..63).
// ---------------------------------------------------------------------------
__global__ __launch_bounds__(64) void attn_kernel(
    const unsigned short* __restrict__ qt,
    const unsigned short* __restrict__ kt,
    const unsigned short* __restrict__ vtl,
    unsigned short* __restrict__ pacc,   // [NS][T32][128][32] bf16
    float* __restrict__ pm,
    float* __restrict__ pl)
{
    const int bid  = blockIdx.x;
    const int xcd  = bid & 7;
    const int b    = xcd >> 1;                // batch <-> XCD pair
    const int par  = xcd & 1;
    const int idx  = bid >> 3;                // 0..255 within XCD
    const int s    = idx & 3;                 // split (NS=4)
    const int trk  = idx >> 2;                // 0..63 tile-rank on this XCD
    const int t32b = (NT32 - 1) - (trk * 2 + par);   // longest first
    const int q0   = t32b * 32;
    const int t32  = b * NT32 + t32b;
    const int lane = threadIdx.x & 63;
    const int l31  = lane & 31;
    const int hih  = lane >> 5;

    const int nkv   = q0 + 32;
    const int chunk = ((nkv + NS * 32 - 1) / (NS * 32)) * 32;
    const int lo    = s * chunk;
    const int hikv  = (lo + chunk < nkv) ? lo + chunk : nkv;
    const size_t mlbase = (size_t)(s * T32 + t32) * 32;

    if (lo >= hikv) {
        if (lane < 32) { pm[mlbase + l31] = -3.0e38f; pl[mlbase + l31] = 0.f; }
        return;
    }

    // Q fragments (coalesced tiled loads)
    const unsigned short* qtb =
        qt + ((size_t)((b * NT32 + t32b) * 8) << 9) + lane * 8;
    short8 qa[8];
#pragma unroll
    for (int ks = 0; ks < 8; ++ks) qa[ks] = ld8(qtb + (ks << 9));

    floatx16 acco[4];
#pragma unroll
    for (int db = 0; db < 4; ++db)
#pragma unroll
        for (int i = 0; i < 16; ++i) acco[db][i] = 0.f;
    float m_r = -3.0e38f, l_r = 0.f;

    for (int kv0 = lo; kv0 < hikv; kv0 += 32) {
        const int t = kv0 >> 5;
        const unsigned short* ktb =
            kt + ((size_t)((b * NT32 + t) * 8) << 9) + lane * 8;
        const unsigned short* vtb =
            vtl + ((size_t)((b * NT32 + t) * 8) << 9) + lane * 8;

        // ---- scores S^T[kv][q] = mfma(K, Q) ----
        floatx16 sc;
#pragma unroll
        for (int i = 0; i < 16; ++i) sc[i] = 0.f;
#pragma unroll
        for (int ks = 0; ks < 8; ++ks) {
            short8 kf = ld8(ktb + (ks << 9));
            sc = __builtin_amdgcn_mfma_f32_32x32x16_bf16(kf, qa[ks], sc, 0, 0, 0);
        }
        // ---- causal mask: only the diagonal tile ----
        if (kv0 == q0) {
#pragma unroll
            for (int r = 0; r < 16; ++r) {
                const int kvloc = (r & 3) + 8 * (r >> 2) + 4 * hih;
                if (kvloc > l31) sc[r] = -3.0e38f;
            }
        }
        // ---- lane-local max (tree) + cross-half ----
        float t8[8];
#pragma unroll
        for (int i = 0; i < 8; ++i) t8[i] = fmaxf(sc[i], sc[i + 8]);
        float t4a = fmaxf(t8[0], t8[4]), t4b = fmaxf(t8[1], t8[5]);
        float t4c = fmaxf(t8[2], t8[6]), t4d = fmaxf(t8[3], t8[7]);
        float pmax = fmaxf(fmaxf(t4a, t4b), fmaxf(t4c, t4d));
        pmax = fmaxf(pmax, __shfl_xor(pmax, 32));
        // ---- deferred rescale (T13, THR=8) ----
        if (__any(pmax > m_r + 8.f)) {
            const float mn  = fmaxf(m_r, pmax);
            const float fac = __expf(m_r - mn);
            m_r = mn; l_r *= fac;
#pragma unroll
            for (int db = 0; db < 4; ++db)
#pragma unroll
                for (int i = 0; i < 16; ++i) acco[db][i] *= fac;
        }
        // ---- p = exp(s - m), lane-local sum ----
        float p[16];
#pragma unroll
        for (int r = 0; r < 16; ++r) p[r] = __expf(sc[r] - m_r);
        float s8[8];
#pragma unroll
        for (int i = 0; i < 8; ++i) s8[i] = p[i] + p[i + 8];
        float s4a = s8[0] + s8[4], s4b = s8[1] + s8[5];
        float s4c = s8[2] + s8[6], s4d = s8[3] + s8[7];
        float ps = (s4a + s4b) + (s4c + s4d);
        ps += __shfl_xor(ps, 32);
        l_r += ps;
        // ---- pack P^T B-fragments (T12: cvt_pk + permlane32_swap) ----
        u32 pk0 = cvtpk_bf16(p[0], p[1]),   pk2 = cvtpk_bf16(p[4], p[5]);
        swap_halves(pk0, pk2);
        u32 pk1 = cvtpk_bf16(p[2], p[3]),   pk3 = cvtpk_bf16(p[6], p[7]);
        swap_halves(pk1, pk3);
        u32 pk4 = cvtpk_bf16(p[8], p[9]),   pk6 = cvtpk_bf16(p[12], p[13]);
        swap_halves(pk4, pk6);
        u32 pk5 = cvtpk_bf16(p[10], p[11]), pk7 = cvtpk_bf16(p[14], p[15]);
        swap_halves(pk5, pk7);
        union { u32 u[4]; short8 s8v; } ua, ub;
        ua.u[0] = pk0; ua.u[1] = pk1; ua.u[2] = pk2; ua.u[3] = pk3;
        ub.u[0] = pk4; ub.u[1] = pk5; ub.u[2] = pk6; ub.u[3] = pk7;
        const short8 pa0 = ua.s8v, pa1 = ub.s8v;
        // ---- PV: O^T[d][q] += V^T x P^T (coalesced tiled V loads) ----
#pragma unroll
        for (int db = 0; db < 4; ++db) {
            short8 vf0 = ld8(vtb + ((db * 2)     << 9));
            acco[db] = __builtin_amdgcn_mfma_f32_32x32x16_bf16(vf0, pa0, acco[db], 0, 0, 0);
            short8 vf1 = ld8(vtb + ((db * 2 + 1) << 9));
            acco[db] = __builtin_amdgcn_mfma_f32_32x32x16_bf16(vf1, pa1, acco[db], 0, 0, 0);
        }
    }

    // ---- write partials (bf16, transposed, coalesced over q) ----
    unsigned short* pt = pacc + (size_t)(s * T32 + t32) * 128 * 32;
#pragma unroll
    for (int db = 0; db < 4; ++db)
#pragma unroll
        for (int r = 0; r < 16; ++r) {
            const int dloc = db * 32 + (r & 3) + 8 * (r >> 2) + 4 * hih;
            pt[(size_t)dloc * 32 + l31] = (unsigned short)f2bf(acco[db][r]);
        }
    if (lane < 32) { pm[mlbase + l31] = m_r; pl[mlbase + l31] = l_r; }
}

// ---------------------------------------------------------------------------
// Combine NS bf16 partials per 32-row tile; LDS transpose for coalesced output.
// ---------------------------------------------------------------------------
__global__ __launch_bounds__(256) void combine_kernel(
    const unsigned short* __restrict__ pacc, const float* __restrict__ pm,
    const float* __restrict__ pl, float* __restrict__ out)
{
    __shared__ float wlds[NS][32];
    __shared__ float tlds[128][33];
    const int t32 = blockIdx.x;
    const int tid = threadIdx.x;

    if (tid < 32) {
        const int q = tid;
        float ms[NS], ls[NS];
        float M = -3.0e38f;
#pragma unroll
        for (int s = 0; s < NS; ++s) {
            ms[s] = pm[(size_t)(s * T32 + t32) * 32 + q];
            ls[s] = pl[(size_t)(s * T32 + t32) * 32 + q];
            M = fmaxf(M, ms[s]);
        }
        float w[NS], den = 0.f;
#pragma unroll
        for (int s = 0; s < NS; ++s) { w[s] = __expf(ms[s] - M); den += w[s] * ls[s]; }
        const float inv = 1.f / den;
#pragma unroll
        for (int s = 0; s < NS; ++s) wlds[s][q] = w[s] * inv;
    }
    __syncthreads();

#pragma unroll
    for (int rep = 0; rep < 16; ++rep) {
        const int flat = rep * 256 + tid;
        const int d = flat >> 5, q = flat & 31;
        float acc = 0.f;
#pragma unroll
        for (int s = 0; s < NS; ++s)
            acc += wlds[s][q] *
                   bf2f(pacc[((size_t)(s * T32 + t32) * 128 + d) * 32 + q]);
        tlds[d][q] = acc;
    }
    __syncthreads();

    const size_t row0 = (size_t)t32 * 32;
#pragma unroll
    for (int rep = 0; rep < 16; ++rep) {
        const int flat = rep * 256 + tid;
        const int q = flat >> 7, d = flat & 127;
        out[(row0 + q) * 128 + d] = tlds[d][q];
    }
}

// ---------------------------------------------------------------------------
extern "C" void kernel_launch(void* const* d_in, const int* in_sizes, int n_in,
                              void* d_out, int out_size, void* d_ws, size_t ws_size,
                              hipStream_t stream)
{
    const float* x  = (const float*)d_in[0];
    const float* Wq = (const float*)d_in[1];
    const float* Wk = (const float*)d_in[2];
    const float* Wv = (const float*)d_in[3];
    float* out = (float*)d_out;

    const size_t TBUF = (size_t)BATCH * NT32 * 8 * 512;           // 2M shorts = 4MB

    unsigned short* wbf  = (unsigned short*)d_ws;                 // 384*1024 bf16
    unsigned short* qt   = wbf + (size_t)384 * DMODEL;
    unsigned short* ktb  = qt + TBUF;
    unsigned short* vtl  = ktb + TBUF;
    unsigned short* pacc = vtl + TBUF;                            // NS*512*128*32 bf16 = 16MB
    float* pm = (float*)(pacc + (size_t)NS * T32 * 128 * 32);
    float* pl = pm + (size_t)NS * T32 * 32;
    // total ~29.3 MB

    const int n8w3 = 3 * HDIM * DMODEL / 8;
    cvt_w_kernel<<<(n8w3 + 255) / 256, 256, 0, stream>>>(Wq, Wk, Wv, wbf);

    qkv_kernel<<<(MROWS / BM) * (384 / BN), 256, 0, stream>>>(x, wbf, qt, ktb, vtl);

    attn_kernel<<<T32 * NS, 64, 0, stream>>>(qt, ktb, vtl, pacc, pm, pl);

    combine_kernel<<<T32, 256, 0, stream>>>(pacc, pm, pl, out);
}